// Round 18
// baseline (185.888 us; speedup 1.0000x reference)
//
#include <hip/hip_runtime.h>
#include <stdint.h>
#include <stddef.h>

typedef _Float16 f16;
typedef f16 f16x8 __attribute__((ext_vector_type(8)));
typedef f16 f16x4 __attribute__((ext_vector_type(4)));
typedef f16 f16x2 __attribute__((ext_vector_type(2)));
typedef float f32x4 __attribute__((ext_vector_type(4)));
typedef float f32x16 __attribute__((ext_vector_type(16)));
typedef unsigned int u32x4 __attribute__((ext_vector_type(4)));

#define SEQ 2048
#define DM 1024
#define NH 16
#define DK 64
#define MTOT 8192   // B*S = 4*2048

// async global->LDS, 16B per lane. LDS dest is wave-uniform base (+lane*16 by HW).
__device__ __forceinline__ void gload16(const f16* g, f16* l) {
    __builtin_amdgcn_global_load_lds(
        (const __attribute__((address_space(1))) uint32_t*)g,
        (__attribute__((address_space(3))) uint32_t*)l,
        16, 0, 0);
}

__device__ __forceinline__ unsigned int pkrtz(float a, float b) {
    return __builtin_bit_cast(unsigned int, __builtin_amdgcn_cvt_pkrtz(a, b));
}

__device__ __forceinline__ void plswap(unsigned int& a, unsigned int& b) {
    auto r = __builtin_amdgcn_permlane32_swap(a, b, false, false);
    unsigned int n0 = r[0], n1 = r[1];
    a = n0; b = n1;
}
__device__ __forceinline__ float xhalf_sum(float x) {
    unsigned int ux = __builtin_bit_cast(unsigned int, x);
    auto r = __builtin_amdgcn_permlane32_swap(ux, ux, false, false);
    unsigned int n0 = r[0], n1 = r[1];
    return __builtin_bit_cast(float, n0) + __builtin_bit_cast(float, n1);
}

// ---------------- fp32 -> fp16 converts (x + 4 weights, single dispatch) ----------------
__global__ void cvt_all(const float* __restrict__ x,
                        const float* __restrict__ w0, const float* __restrict__ w1,
                        const float* __restrict__ w2, const float* __restrict__ w3,
                        f16* __restrict__ xh,
                        f16* __restrict__ d0, f16* __restrict__ d1,
                        f16* __restrict__ d2, f16* __restrict__ d3) {
    int bid = blockIdx.x;
    const float* s;
    f16* d;
    int off;
    if (bid < 4096) { s = x; d = xh; off = bid; }
    else {
        int t = bid - 4096;
        int which = t >> 9;
        off = t & 511;
        s = which == 0 ? w0 : which == 1 ? w1 : which == 2 ? w2 : w3;
        d = which == 0 ? d0 : which == 1 ? d1 : which == 2 ? d2 : d3;
    }
    int i = (off * 256 + threadIdx.x) * 8;
    float4 a = *(const float4*)(s + i);
    float4 b = *(const float4*)(s + i + 4);
    f16x8 o = {(f16)a.x, (f16)a.y, (f16)a.z, (f16)a.w,
               (f16)b.x, (f16)b.y, (f16)b.z, (f16)b.w};
    *(f16x8*)(d + i) = o;
}

// ---------------- QKV projection: 256x256 tile, BK=64, 8-wave, 8-phase ----------------
// T2 (XOR swizzle) + T3/T4 (per-phase stage, counted pipeline) + T5 (setprio).
// grid 384 = 32 bm x 12 bn (bn: 4 per Q/K/V). Per wave: 128x64 output.
// LDS: double-buffered A/B panels (2 x 2half x 128x64 f16 each) = 128 KB.
// Race-freedom: stage(t+1) writes slot (t+1)&1, last read at tile t-1 — the
// tile-entry barrier fences all waves past those reads before any stage issues.
__global__ __launch_bounds__(512, 2)
void gemm_qkv8(const f16* __restrict__ A,
               const f16* __restrict__ W0, const f16* __restrict__ W1, const f16* __restrict__ W2,
               const float* __restrict__ b0, const float* __restrict__ b1, const float* __restrict__ b2,
               f16* __restrict__ Qo, f16* __restrict__ Ko, f16* __restrict__ Vto) {
    __shared__ __align__(16) f16 Asl[2][2][128 * 64];   // [slot][half][row][col]
    __shared__ __align__(16) f16 Bsl[2][2][128 * 64];
    const int tid = threadIdx.x;
    const int w = tid >> 6, lane = tid & 63;
    const int g = lane >> 4, c16 = lane & 15;
    const int wr = w >> 2, wc = w & 3;
    const int srow = lane >> 3, scol = lane & 7;
    const int bid = blockIdx.x;
    const int wg = (bid & 7) * 48 + (bid >> 3);   // 384 % 8 == 0 -> bijective
    const int bm = wg / 12, bn = wg % 12;
    const int which = bn >> 2, bnm = bn & 3;
    const f16* Bw = which == 0 ? W0 : which == 1 ? W1 : W2;
    const float* bias = which == 0 ? b0 : which == 1 ? b1 : b2;
    const float oscale = (which == 0) ? 0.18033688f : 1.0f;
    const int mode = (which == 2) ? 1 : 0;
    void* outp = which == 0 ? (void*)Qo : which == 1 ? (void*)Ko : (void*)Vto;

    const f16* Ab = A + (size_t)bm * 256 * DM;
    const f16* Bb = Bw + (size_t)bnm * 256 * DM;
    const int csw = (scol ^ srow) * 8;            // pre-swizzled source column

    // stage one 128x64 half (2 gloads/thread)
#define STAGE_A(slot, half, kt)                                                     \
    {                                                                               \
        _Pragma("unroll")                                                           \
        for (int i_ = 0; i_ < 2; ++i_) {                                            \
            int row_ = (half) * 128 + i_ * 64 + w * 8 + srow;                       \
            gload16(Ab + (size_t)row_ * DM + (kt) * 64 + csw,                       \
                    &Asl[slot][half][(i_ * 64 + w * 8) * 64]);                      \
        }                                                                           \
    }
#define STAGE_B(slot, half, kt)                                                     \
    {                                                                               \
        _Pragma("unroll")                                                           \
        for (int i_ = 0; i_ < 2; ++i_) {                                            \
            int row_ = (half) * 128 + i_ * 64 + w * 8 + srow;                       \
            gload16(Bb + (size_t)row_ * DM + (kt) * 64 + csw,                       \
                    &Bsl[slot][half][(i_ * 64 + w * 8) * 64]);                      \
        }                                                                           \
    }

    f32x4 acc[8][4] = {};
    f16x8 bfr[4];
    const int rsw = (c16 & 7) << 4;               // read swizzle (row&7 == c16&7)

    STAGE_A(0, 0, 0); STAGE_A(0, 1, 0); STAGE_B(0, 0, 0); STAGE_B(0, 1, 0);

    for (int kt = 0; kt < 16; ++kt) {
        const int slot = kt & 1, nslot = slot ^ 1;
        asm volatile("s_waitcnt vmcnt(0)" ::: "memory");   // tile kt resident
        __builtin_amdgcn_s_barrier();

        const char* Ah = (const char*)&Asl[slot][wr][0];
        const char* Bh = (const char*)&Bsl[slot][wc >> 1][0];
        const int brow0 = (wc & 1) * 64;

#pragma unroll
        for (int p = 0; p < 4; ++p) {
            const int mh = p & 1, kk = p >> 1;
            const int ko = (kk * 64 + g * 16);
            f16x8 afr[4];
#pragma unroll
            for (int mi = 0; mi < 4; ++mi) {
                int row = mh * 64 + mi * 16 + c16;
                afr[mi] = *(const f16x8*)(Ah + row * 128 + (ko ^ rsw));
            }
            if (mh == 0) {
#pragma unroll
                for (int ni = 0; ni < 4; ++ni) {
                    int row = brow0 + ni * 16 + c16;
                    bfr[ni] = *(const f16x8*)(Bh + row * 128 + (ko ^ rsw));
                }
            }
            if (kt + 1 < 16) {                    // stage half p of tile kt+1
                if (p == 0)      STAGE_A(nslot, 0, kt + 1)
                else if (p == 1) STAGE_A(nslot, 1, kt + 1)
                else if (p == 2) STAGE_B(nslot, 0, kt + 1)
                else             STAGE_B(nslot, 1, kt + 1)
            }
            __builtin_amdgcn_s_barrier();
            __builtin_amdgcn_s_setprio(1);
#pragma unroll
            for (int mi = 0; mi < 4; ++mi)
#pragma unroll
                for (int ni = 0; ni < 4; ++ni)
                    acc[mh * 4 + mi][ni] =
                        __builtin_amdgcn_mfma_f32_16x16x32_f16(afr[mi], bfr[ni],
                                                               acc[mh * 4 + mi][ni], 0, 0, 0);
            __builtin_amdgcn_s_setprio(0);
            __builtin_amdgcn_s_barrier();
        }
    }
#undef STAGE_A
#undef STAGE_B

    // epilogue (register-only)
#pragma unroll
    for (int mi = 0; mi < 8; ++mi) {
#pragma unroll
        for (int ni = 0; ni < 4; ++ni) {
            const int col = bnm * 256 + wc * 64 + ni * 16 + c16;   // within 1024
            const float bv = bias[col];
            const int row0 = bm * 256 + wr * 128 + mi * 16 + g * 4;
            if (mode == 1) {
                int b = row0 >> 11, s0 = row0 & 2047;
                int h = col >> 6, d = col & 63;
                f16x4 pv;
#pragma unroll
                for (int j = 0; j < 4; ++j) pv[j] = (f16)((acc[mi][ni][j] + bv));
                *(f16x4*)((f16*)outp + (((size_t)(b * NH + h) * DK + d) * SEQ + s0)) = pv;
            } else {
#pragma unroll
                for (int j = 0; j < 4; ++j) {
                    int row = row0 + j;
                    int b = row >> 11, s = row & 2047;
                    int h = col >> 6, d = col & 63;
                    ((f16*)outp)[((size_t)(b * NH + h) * SEQ + s) * DK + d] =
                        (f16)((acc[mi][ni][j] + bv) * oscale);
                }
            }
        }
    }
}

// ---------------- out-GEMM (m97 structure, unchanged) ----------------
__device__ __forceinline__
void gemm_body(const f16* __restrict__ A, const f16* __restrict__ Bw,
               const float* __restrict__ bias, float* __restrict__ outp,
               int bm, int bn, f16* As, f16* Bs) {
    const int tid = threadIdx.x;
    const int w = tid >> 6, lane = tid & 63;
    const int g = lane >> 4, c16 = lane & 15;
    const int wr = w >> 1, wc = w & 1;
    const int r8 = lane >> 3, co = (lane & 7) * 8;

    f32x4 acc[4][4] = {};

    const f16* Ab = A + (size_t)bm * 128 * DM;
    const f16* Bb = Bw + (size_t)bn * 128 * DM;

    for (int kt = 0; kt < DM / 64; ++kt) {
        if (kt) __syncthreads();
        const f16* As_src = Ab + kt * 64;
        const f16* Bs_src = Bb + kt * 64;
#pragma unroll
        for (int i = 0; i < 4; ++i) {
            int c = 4 * w + i;
            gload16(As_src + (size_t)(c * 8 + r8) * DM + co, As + c * 512);
            gload16(Bs_src + (size_t)(c * 8 + r8) * DM + co, Bs + c * 512);
        }
        __syncthreads();
#pragma unroll
        for (int kk = 0; kk < 2; ++kk) {
            f16x8 a[4], b[4];
            const int ko = kk * 32 + g * 8;
#pragma unroll
            for (int m = 0; m < 4; ++m)
                a[m] = *(const f16x8*)(As + (wr * 64 + m * 16 + c16) * 64 + ko);
#pragma unroll
            for (int n = 0; n < 4; ++n)
                b[n] = *(const f16x8*)(Bs + (wc * 64 + n * 16 + c16) * 64 + ko);
#pragma unroll
            for (int m = 0; m < 4; ++m)
#pragma unroll
                for (int n = 0; n < 4; ++n)
                    acc[m][n] = __builtin_amdgcn_mfma_f32_16x16x32_f16(a[m], b[n], acc[m][n], 0, 0, 0);
        }
    }

#pragma unroll
    for (int m = 0; m < 4; ++m) {
#pragma unroll
        for (int n = 0; n < 4; ++n) {
            const int col = bn * 128 + wc * 64 + n * 16 + c16;
            const float bv = bias[col];
            const int row0 = bm * 128 + wr * 64 + m * 16 + g * 4;
#pragma unroll
            for (int j = 0; j < 4; ++j) {
                int row = row0 + j;
                outp[(size_t)row * DM + col] = acc[m][n][j] + bv;
            }
        }
    }
}

__global__ __launch_bounds__(256, 2)
void gemm_out(const f16* __restrict__ A, const f16* __restrict__ Wo,
              const float* __restrict__ bias, float* __restrict__ outp) {
    __shared__ __align__(16) f16 As[128 * 64];
    __shared__ __align__(16) f16 Bs[128 * 64];
    const int bid = blockIdx.x;
    const int wg = (bid & 7) * 64 + (bid >> 3);
    gemm_body(A, Wo, bias, outp, wg >> 3, wg & 7, As, Bs);
}

// ---------------- flash attention: 8-wave block, role-split pipeline (R17) ----------------
__global__ __launch_bounds__(512, 1)
void attn(const f16* __restrict__ Qg, const f16* __restrict__ Kg,
          const f16* __restrict__ Vg, f16* __restrict__ ctx) {
    __shared__ __align__(16) f16 SM[4][2][64 * 64];   // [slot][0=K,1=V][64x64 tile]
    const int tid = threadIdx.x;
    const int w = tid >> 6, lane = tid & 63;
    const int q31 = lane & 31, hi = lane >> 5;
    const int bid = blockIdx.x;
    const int wg = (bid & 7) * 32 + (bid >> 3);    // XCD swizzle, 256%8==0
    const int bh = wg >> 2, qt = wg & 3;
    const int b = bh >> 4, h = bh & 15;
    const f16* Qp = Qg + (size_t)bh * SEQ * DK;
    const f16* Kp = Kg + (size_t)bh * SEQ * DK;
    const f16* Vp = Vg + (size_t)bh * DK * SEQ;
    const int q0w = qt * 512 + w * 64;             // 64 q rows per wave

    f16x8 qfA[4], qfB[4];
#pragma unroll
    for (int ks4 = 0; ks4 < 4; ++ks4) {
        qfA[ks4] = *(const f16x8*)(Qp + (size_t)(q0w + q31) * DK + ks4 * 16 + hi * 8);
        qfB[ks4] = *(const f16x8*)(Qp + (size_t)(q0w + 32 + q31) * DK + ks4 * 16 + hi * 8);
    }

    const f32x16 z = {};
    const f16x2 one2 = {(f16)1.0f, (f16)1.0f};
    f32x16 OA0 = {}, OA1 = {}, OB0 = {}, OB1 = {};
    float lrA = 0.f, lrB = 0.f;

    const int srow = lane >> 3;
    const int scol = lane & 7;
    const int fsw = (q31 & 7) << 4;

#define STAGE(bufi, kvoff)                                                        \
    {                                                                             \
        int row_ = w * 8 + srow;                                                  \
        int csw_ = (scol ^ (row_ & 7)) * 8;                                       \
        gload16(Kp + (size_t)((kvoff) + row_) * DK + csw_, &SM[bufi][0][w * 512]); \
        gload16(Vp + (size_t)row_ * SEQ + (kvoff) + csw_, &SM[bufi][1][w * 512]);  \
    }

    auto qk = [&](const char* Kb, f32x16& A0, f32x16& A1, f32x16& B0, f32x16& B1) {
#pragma unroll
        for (int ks4 = 0; ks4 < 4; ++ks4) {
            const int off = (ks4 * 32 + hi * 16) ^ fsw;
            f16x8 kf0 = *(const f16x8*)(Kb + q31 * 128 + off);
            f16x8 kf1 = *(const f16x8*)(Kb + (32 + q31) * 128 + off);
            if (ks4 == 0) {
                A0 = __builtin_amdgcn_mfma_f32_32x32x16_f16(kf0, qfA[0], z, 0, 0, 0);
                B0 = __builtin_amdgcn_mfma_f32_32x32x16_f16(kf0, qfB[0], z, 0, 0, 0);
                A1 = __builtin_amdgcn_mfma_f32_32x32x16_f16(kf1, qfA[0], z, 0, 0, 0);
                B1 = __builtin_amdgcn_mfma_f32_32x32x16_f16(kf1, qfB[0], z, 0, 0, 0);
            } else {
                A0 = __builtin_amdgcn_mfma_f32_32x32x16_f16(kf0, qfA[ks4], A0, 0, 0, 0);
                B0 = __builtin_amdgcn_mfma_f32_32x32x16_f16(kf0, qfB[ks4], B0, 0, 0, 0);
                A1 = __builtin_amdgcn_mfma_f32_32x32x16_f16(kf1, qfA[ks4], A1, 0, 0, 0);
                B1 = __builtin_amdgcn_mfma_f32_32x32x16_f16(kf1, qfB[ks4], B1, 0, 0, 0);
            }
        }
    };

    auto pv = [&](const char* Vb, f16x8 (&pA)[4], f16x8 (&pB)[4]) {
#pragma unroll
        for (int ksl = 0; ksl < 4; ++ksl) {
            const int off = (ksl * 32 + hi * 16) ^ fsw;
            f16x8 vf0 = *(const f16x8*)(Vb + q31 * 128 + off);
            f16x8 vf1 = *(const f16x8*)(Vb + (32 + q31) * 128 + off);
            OA0 = __builtin_amdgcn_mfma_f32_32x32x16_f16(vf0, pA[ksl], OA0, 0, 0, 0);
            OA1 = __builtin_amdgcn_mfma_f32_32x32x16_f16(vf1, pA[ksl], OA1, 0, 0, 0);
            OB0 = __builtin_amdgcn_mfma_f32_32x32x16_f16(vf0, pB[ksl], OB0, 0, 0, 0);
            OB1 = __builtin_amdgcn_mfma_f32_32x32x16_f16(vf1, pB[ksl], OB1, 0, 0, 0);
        }
    };

    auto soft32 = [&](f32x16& sp, f16x8& paLo, f16x8& paHi, float& ls) {
#pragma unroll
        for (int r = 0; r < 16; ++r) sp[r] = __builtin_amdgcn_exp2f(sp[r]);
        unsigned int u[8];
#pragma unroll
        for (int j = 0; j < 4; ++j) {
            u[2 * j]     = pkrtz(sp[4 * j], sp[4 * j + 1]);
            u[2 * j + 1] = pkrtz(sp[4 * j + 2], sp[4 * j + 3]);
        }
        float ls0 = 0.f, ls1 = 0.f;
#pragma unroll
        for (int j = 0; j < 4; ++j) {
            ls0 = __builtin_amdgcn_fdot2(__builtin_bit_cast(f16x2, u[2 * j]), one2, ls0, false);
            ls1 = __builtin_amdgcn_fdot2(__builtin_bit_cast(f16x2, u[2 * j + 1]), one2, ls1, false);
        }
        ls += ls0 + ls1;
        plswap(u[0], u[2]);
        plswap(u[1], u[3]);
        plswap(u[4], u[6]);
        plswap(u[5], u[7]);
        u32x4 t0w = {u[0], u[1], u[2], u[3]};
        u32x4 t1w = {u[4], u[5], u[6], u[7]};
        paLo = __builtin_bit_cast(f16x8, t0w);
        paHi = __builtin_bit_cast(f16x8, t1w);
    };

    auto body = [&](int t, f16x8 (&pPA)[4], f16x8 (&pPB)[4],
                           f16x8 (&pCA)[4], f16x8 (&pCB)[4]) {
        if (t + 1 < 32) {
            asm volatile("s_waitcnt vmcnt(2)" ::: "memory");
        } else {
            asm volatile("s_waitcnt vmcnt(0)" ::: "memory");
        }
        __builtin_amdgcn_s_barrier();
        if (t + 2 < 32) STAGE((t + 2) & 3, (t + 2) * 64);

        const char* Kb = (const char*)&SM[t & 3][0][0];
        f32x16 sA0, sA1, sB0, sB1;
        if ((w >> 2) == 0) {
            qk(Kb, sA0, sA1, sB0, sB1);
            float lsA = 0.f, lsB = 0.f;
            soft32(sA0, pCA[0], pCA[1], lsA);
            soft32(sB0, pCB[0], pCB[1], lsB);
            soft32(sA1, pCA[2], pCA[3], lsA);
            soft32(sB1, pCB[2], pCB[3], lsB);
            lrA += lsA; lrB += lsB;
            pv((const char*)&SM[t & 3][1][0], pCA, pCB);
        } else {
            if (t > 0) pv((const char*)&SM[(t - 1) & 3][1][0], pPA, pPB);
            qk(Kb, sA0, sA1, sB0, sB1);
            float lsA = 0.f, lsB = 0.f;
            soft32(sA0, pCA[0], pCA[1], lsA);
            soft32(sB0, pCB[0], pCB[1], lsB);
            soft32(sA1, pCA[2], pCA[3], lsA);
            soft32(sB1, pCB[2], pCB[3], lsB);
            lrA += lsA; lrB += lsB;
        }
    };

    STAGE(0, 0);
    STAGE(1, 64);

    f16x8 paEA[4], paEB[4], paOA[4], paOB[4];
#pragma unroll
    for (int i = 0; i < 4; ++i) {
        paOA[i] = (f16x8){};
        paOB[i] = (f16x8){};
    }

    for (int t = 0; t < 32; t += 2) {
        body(t,     paOA, paOB, paEA, paEB);
        body(t + 1, paEA, paEB, paOA, paOB);
    }
    if ((w >> 2) != 0) {
        pv((const char*)&SM[3][1][0], paOA, paOB);
    }
#undef STAGE

    __syncthreads();

    f16* tw = &SM[0][0][0] + w * 4096;
    {
        const float rlA = 1.f / xhalf_sum(lrA);
        const float rlB = 1.f / xhalf_sum(lrB);
#pragma unroll
        for (int f = 0; f < 2; ++f) {
            const float rl = f ? rlB : rlA;
            char* twf = (char*)tw + f * 4096;
#pragma unroll
            for (int dblk = 0; dblk < 2; ++dblk) {
                const f32x16& Op = f ? (dblk ? OB1 : OB0) : (dblk ? OA1 : OA0);
#pragma unroll
                for (int rp = 0; rp < 8; ++rp) {
                    int r = 2 * rp;
                    int d0 = dblk * 32 + (r & 3) + 8 * (r >> 2) + 4 * hi;
                    unsigned int uv = pkrtz(Op[r] * rl, Op[r + 1] * rl);
                    *(unsigned int*)(twf + q31 * 128 + ((d0 * 2) ^ ((q31 & 7) << 4))) = uv;
                }
            }
        }
    }
#pragma unroll
    for (int p4 = 0; p4 < 8; ++p4) {
        int qq = p4 * 8 + (lane >> 3), ch = lane & 7;
        f16x8 v = *(const f16x8*)((const char*)tw + (qq >> 5) * 4096 + (qq & 31) * 128 +
                                  ((ch * 16) ^ ((qq & 7) << 4)));
        *(f16x8*)(ctx + (size_t)(b * SEQ + q0w + qq) * DM + h * DK + ch * 8) = v;
    }
}

extern "C" void kernel_launch(void* const* d_in, const int* in_sizes, int n_in,
                              void* d_out, int out_size, void* d_ws, size_t ws_size,
                              hipStream_t stream) {
    const float* x  = (const float*)d_in[0];
    const float* Wq = (const float*)d_in[1];
    const float* bq = (const float*)d_in[2];
    const float* Wk = (const float*)d_in[3];
    const float* bk = (const float*)d_in[4];
    const float* Wv = (const float*)d_in[5];
    const float* bv = (const float*)d_in[6];
    const float* Wo = (const float*)d_in[7];
    const float* bo = (const float*)d_in[8];

    f16* ws  = (f16*)d_ws;
    f16* xh  = ws;
    f16* Wqh = ws + (size_t)8 * 1024 * 1024;
    f16* Wkh = Wqh + 1024 * 1024;
    f16* Wvh = Wkh + 1024 * 1024;
    f16* Woh = Wvh + 1024 * 1024;
    f16* Vtb = Woh + 1024 * 1024;
    f16* Qb = (f16*)d_out;
    f16* Kb = Qb + (size_t)8 * 1024 * 1024;
    f16* ctx = xh;

    cvt_all<<<4096 + 4 * 512, 256, 0, stream>>>(x, Wq, Wk, Wv, Wo, xh, Wqh, Wkh, Wvh, Woh);

    gemm_qkv8<<<384, 512, 0, stream>>>(xh, Wqh, Wkh, Wvh, bq, bk, bv, Qb, Kb, Vtb);

    attn<<<256, 512, 0, stream>>>(Qb, Kb, Vtb, ctx);

    gemm_out<<<512, 256, 0, stream>>>(ctx, Woh, bo, (float*)d_out);
}

// Round 19
// 177.462 us; speedup vs baseline: 1.0475x; 1.0475x over previous
//
#include <hip/hip_runtime.h>
#include <stdint.h>
#include <stddef.h>

typedef _Float16 f16;
typedef f16 f16x8 __attribute__((ext_vector_type(8)));
typedef f16 f16x4 __attribute__((ext_vector_type(4)));
typedef f16 f16x2 __attribute__((ext_vector_type(2)));
typedef float f32x4 __attribute__((ext_vector_type(4)));
typedef float f32x16 __attribute__((ext_vector_type(16)));
typedef unsigned int u32x4 __attribute__((ext_vector_type(4)));

#define SEQ 2048
#define DM 1024
#define NH 16
#define DK 64
#define MTOT 8192   // B*S = 4*2048

// async global->LDS, 16B per lane. LDS dest is wave-uniform base (+lane*16 by HW).
__device__ __forceinline__ void gload16(const f16* g, f16* l) {
    __builtin_amdgcn_global_load_lds(
        (const __attribute__((address_space(1))) uint32_t*)g,
        (__attribute__((address_space(3))) uint32_t*)l,
        16, 0, 0);
}

__device__ __forceinline__ unsigned int pkrtz(float a, float b) {
    return __builtin_bit_cast(unsigned int, __builtin_amdgcn_cvt_pkrtz(a, b));
}

__device__ __forceinline__ void plswap(unsigned int& a, unsigned int& b) {
    auto r = __builtin_amdgcn_permlane32_swap(a, b, false, false);
    unsigned int n0 = r[0], n1 = r[1];
    a = n0; b = n1;
}
__device__ __forceinline__ float xhalf_sum(float x) {
    unsigned int ux = __builtin_bit_cast(unsigned int, x);
    auto r = __builtin_amdgcn_permlane32_swap(ux, ux, false, false);
    unsigned int n0 = r[0], n1 = r[1];
    return __builtin_bit_cast(float, n0) + __builtin_bit_cast(float, n1);
}

// ---------------- fp32 -> fp16 converts (x + 4 weights, single dispatch) ----------------
__global__ void cvt_all(const float* __restrict__ x,
                        const float* __restrict__ w0, const float* __restrict__ w1,
                        const float* __restrict__ w2, const float* __restrict__ w3,
                        f16* __restrict__ xh,
                        f16* __restrict__ d0, f16* __restrict__ d1,
                        f16* __restrict__ d2, f16* __restrict__ d3) {
    int bid = blockIdx.x;
    const float* s;
    f16* d;
    int off;
    if (bid < 4096) { s = x; d = xh; off = bid; }
    else {
        int t = bid - 4096;
        int which = t >> 9;
        off = t & 511;
        s = which == 0 ? w0 : which == 1 ? w1 : which == 2 ? w2 : w3;
        d = which == 0 ? d0 : which == 1 ? d1 : which == 2 ? d2 : d3;
    }
    int i = (off * 256 + threadIdx.x) * 8;
    float4 a = *(const float4*)(s + i);
    float4 b = *(const float4*)(s + i + 4);
    f16x8 o = {(f16)a.x, (f16)a.y, (f16)a.z, (f16)a.w,
               (f16)b.x, (f16)b.y, (f16)b.z, (f16)b.w};
    *(f16x8*)(d + i) = o;
}

// ---------------- 256x128 8-wave 2-phase GEMM body (T2+T3/T4+T5, balanced) ----------------
// BM=256, BN=128, BK=64. 8 waves (4x2), 64x64 out/wave, acc = 64 VGPR.
// LDS: A 2x(256x64) + B 2x(128x64) = 96 KB, double-buffered.
// Per K-tile: {vmcnt(0); barrier} + 2 phases {8 ds_read || 3 stage; barrier;
// setprio(1) 16 MFMA setprio(0)}. Stage(t+1) -> slot (t+1)&1, whose readers
// finished before this tile's entry barrier (own-vmcnt + barrier => resident).
__device__ __forceinline__
void gemm256_body(const f16* __restrict__ Ab, const f16* __restrict__ Bb,
                  const float* __restrict__ bias, void* __restrict__ outp,
                  int mode, float oscale, int bm, int colbase,
                  f16* Asl, f16* Bsl) {
    const int tid = threadIdx.x;
    const int w = tid >> 6, lane = tid & 63;
    const int g = lane >> 4, c16 = lane & 15;
    const int wr = w >> 1, wc = w & 1;
    const int srow = lane >> 3, scol = lane & 7;
    const int csw = (scol ^ srow) * 8;            // pre-swizzled source column
    const int rsw = (c16 & 7) << 4;               // read swizzle (row&7 == c16&7)

    f32x4 acc[4][4] = {};

#define SA(slot, i_, kt) gload16(Ab + (size_t)((w * 4 + (i_)) * 8 + srow) * DM + (kt) * 64 + csw, \
                                 Asl + (slot) * 16384 + (w * 4 + (i_)) * 512)
#define SB(slot, i_, kt) gload16(Bb + (size_t)((w * 2 + (i_)) * 8 + srow) * DM + (kt) * 64 + csw, \
                                 Bsl + (slot) * 8192 + (w * 2 + (i_)) * 512)

    SA(0, 0, 0); SA(0, 1, 0); SA(0, 2, 0); SA(0, 3, 0); SB(0, 0, 0); SB(0, 1, 0);

    for (int kt = 0; kt < 16; ++kt) {
        const int slot = kt & 1, ns = slot ^ 1;
        asm volatile("s_waitcnt vmcnt(0)" ::: "memory");   // tile kt resident (own loads)
        __builtin_amdgcn_s_barrier();                      // + everyone's
        const char* Ah = (const char*)(Asl + slot * 16384);
        const char* Bh = (const char*)(Bsl + slot * 8192);
#pragma unroll
        for (int p = 0; p < 2; ++p) {
            f16x8 afr[4], bfr[4];
            const int ko = p * 64 + g * 16;
#pragma unroll
            for (int mi = 0; mi < 4; ++mi) {
                int row = wr * 64 + mi * 16 + c16;
                afr[mi] = *(const f16x8*)(Ah + row * 128 + (ko ^ rsw));
            }
#pragma unroll
            for (int ni = 0; ni < 4; ++ni) {
                int row = wc * 64 + ni * 16 + c16;
                bfr[ni] = *(const f16x8*)(Bh + row * 128 + (ko ^ rsw));
            }
            if (kt + 1 < 16) {                    // stage half p of tile kt+1
                if (p == 0) { SA(ns, 0, kt + 1); SA(ns, 1, kt + 1); SB(ns, 0, kt + 1); }
                else        { SA(ns, 2, kt + 1); SA(ns, 3, kt + 1); SB(ns, 1, kt + 1); }
            }
            __builtin_amdgcn_s_barrier();
            __builtin_amdgcn_s_setprio(1);
#pragma unroll
            for (int mi = 0; mi < 4; ++mi)
#pragma unroll
                for (int ni = 0; ni < 4; ++ni)
                    acc[mi][ni] = __builtin_amdgcn_mfma_f32_16x16x32_f16(
                        afr[mi], bfr[ni], acc[mi][ni], 0, 0, 0);
            __builtin_amdgcn_s_setprio(0);
        }
    }
#undef SA
#undef SB

    // epilogue (register-only)
#pragma unroll
    for (int mi = 0; mi < 4; ++mi) {
#pragma unroll
        for (int ni = 0; ni < 4; ++ni) {
            const int col = colbase + wc * 64 + ni * 16 + c16;   // within 1024
            const float bv = bias[col];
            const int row0 = bm * 256 + wr * 64 + mi * 16 + g * 4;
            if (mode == 1) {
                int b = row0 >> 11, s0 = row0 & 2047;
                int h = col >> 6, d = col & 63;
                f16x4 pv;
#pragma unroll
                for (int j = 0; j < 4; ++j) pv[j] = (f16)(acc[mi][ni][j] + bv);
                *(f16x4*)((f16*)outp + (((size_t)(b * NH + h) * DK + d) * SEQ + s0)) = pv;
            } else if (mode == 0) {
#pragma unroll
                for (int j = 0; j < 4; ++j) {
                    int row = row0 + j;
                    int b = row >> 11, s = row & 2047;
                    int h = col >> 6, d = col & 63;
                    ((f16*)outp)[((size_t)(b * NH + h) * SEQ + s) * DK + d] =
                        (f16)((acc[mi][ni][j] + bv) * oscale);
                }
            } else {
#pragma unroll
                for (int j = 0; j < 4; ++j) {
                    int row = row0 + j;
                    ((float*)outp)[(size_t)row * DM + col] = acc[mi][ni][j] + bv;
                }
            }
        }
    }
}

// QKV: grid 768 = 32 bm x 24 bn (8 bn per Q/K/V matrix) = 3 exact CU rounds.
__global__ __launch_bounds__(512, 1)
void gemm_qkv8(const f16* __restrict__ A,
               const f16* __restrict__ W0, const f16* __restrict__ W1, const f16* __restrict__ W2,
               const float* __restrict__ b0, const float* __restrict__ b1, const float* __restrict__ b2,
               f16* __restrict__ Qo, f16* __restrict__ Ko, f16* __restrict__ Vto) {
    __shared__ __align__(16) f16 Asl[2 * 256 * 64];
    __shared__ __align__(16) f16 Bsl[2 * 128 * 64];
    const int bid = blockIdx.x;
    const int wg = (bid & 7) * 96 + (bid >> 3);   // 768 % 8 == 0 -> bijective
    const int bm = wg / 24, bn = wg % 24;
    const int which = bn >> 3, bnm = bn & 7;
    const f16* Bw = which == 0 ? W0 : which == 1 ? W1 : W2;
    const float* bias = which == 0 ? b0 : which == 1 ? b1 : b2;
    const float oscale = (which == 0) ? 0.18033688f : 1.0f;   // 0.125*log2e into Q
    const int mode = (which == 2) ? 1 : 0;
    void* outp = which == 0 ? (void*)Qo : which == 1 ? (void*)Ko : (void*)Vto;
    gemm256_body(A + (size_t)bm * 256 * DM, Bw + (size_t)bnm * 128 * DM,
                 bias, outp, mode, oscale, bm, bnm * 128, Asl, Bsl);
}

// out-GEMM: grid 256 = 32 bm x 8 bn = exactly 1 CU round.
__global__ __launch_bounds__(512, 1)
void gemm_out8(const f16* __restrict__ A, const f16* __restrict__ Wo,
               const float* __restrict__ bias, float* __restrict__ outp) {
    __shared__ __align__(16) f16 Asl[2 * 256 * 64];
    __shared__ __align__(16) f16 Bsl[2 * 128 * 64];
    const int bid = blockIdx.x;
    const int wg = (bid & 7) * 32 + (bid >> 3);   // 256 % 8 == 0
    const int bm = wg >> 3, bn = wg & 7;
    gemm256_body(A + (size_t)bm * 256 * DM, Wo + (size_t)bn * 128 * DM,
                 bias, (void*)outp, 2, 1.0f, bm, bn * 128, Asl, Bsl);
}

// ---------------- flash attention: 8-wave block, role-split pipeline (R17, proven) ----------------
__global__ __launch_bounds__(512, 1)
void attn(const f16* __restrict__ Qg, const f16* __restrict__ Kg,
          const f16* __restrict__ Vg, f16* __restrict__ ctx) {
    __shared__ __align__(16) f16 SM[4][2][64 * 64];   // [slot][0=K,1=V][64x64 tile]
    const int tid = threadIdx.x;
    const int w = tid >> 6, lane = tid & 63;
    const int q31 = lane & 31, hi = lane >> 5;
    const int bid = blockIdx.x;
    const int wg = (bid & 7) * 32 + (bid >> 3);    // XCD swizzle, 256%8==0
    const int bh = wg >> 2, qt = wg & 3;
    const int b = bh >> 4, h = bh & 15;
    const f16* Qp = Qg + (size_t)bh * SEQ * DK;
    const f16* Kp = Kg + (size_t)bh * SEQ * DK;
    const f16* Vp = Vg + (size_t)bh * DK * SEQ;
    const int q0w = qt * 512 + w * 64;             // 64 q rows per wave

    f16x8 qfA[4], qfB[4];
#pragma unroll
    for (int ks4 = 0; ks4 < 4; ++ks4) {
        qfA[ks4] = *(const f16x8*)(Qp + (size_t)(q0w + q31) * DK + ks4 * 16 + hi * 8);
        qfB[ks4] = *(const f16x8*)(Qp + (size_t)(q0w + 32 + q31) * DK + ks4 * 16 + hi * 8);
    }

    const f32x16 z = {};
    const f16x2 one2 = {(f16)1.0f, (f16)1.0f};
    f32x16 OA0 = {}, OA1 = {}, OB0 = {}, OB1 = {};
    float lrA = 0.f, lrB = 0.f;

    const int srow = lane >> 3;
    const int scol = lane & 7;
    const int fsw = (q31 & 7) << 4;

#define STAGE(bufi, kvoff)                                                        \
    {                                                                             \
        int row_ = w * 8 + srow;                                                  \
        int csw_ = (scol ^ (row_ & 7)) * 8;                                       \
        gload16(Kp + (size_t)((kvoff) + row_) * DK + csw_, &SM[bufi][0][w * 512]); \
        gload16(Vp + (size_t)row_ * SEQ + (kvoff) + csw_, &SM[bufi][1][w * 512]);  \
    }

    auto qk = [&](const char* Kb, f32x16& A0, f32x16& A1, f32x16& B0, f32x16& B1) {
#pragma unroll
        for (int ks4 = 0; ks4 < 4; ++ks4) {
            const int off = (ks4 * 32 + hi * 16) ^ fsw;
            f16x8 kf0 = *(const f16x8*)(Kb + q31 * 128 + off);
            f16x8 kf1 = *(const f16x8*)(Kb + (32 + q31) * 128 + off);
            if (ks4 == 0) {
                A0 = __builtin_amdgcn_mfma_f32_32x32x16_f16(kf0, qfA[0], z, 0, 0, 0);
                B0 = __builtin_amdgcn_mfma_f32_32x32x16_f16(kf0, qfB[0], z, 0, 0, 0);
                A1 = __builtin_amdgcn_mfma_f32_32x32x16_f16(kf1, qfA[0], z, 0, 0, 0);
                B1 = __builtin_amdgcn_mfma_f32_32x32x16_f16(kf1, qfB[0], z, 0, 0, 0);
            } else {
                A0 = __builtin_amdgcn_mfma_f32_32x32x16_f16(kf0, qfA[ks4], A0, 0, 0, 0);
                B0 = __builtin_amdgcn_mfma_f32_32x32x16_f16(kf0, qfB[ks4], B0, 0, 0, 0);
                A1 = __builtin_amdgcn_mfma_f32_32x32x16_f16(kf1, qfA[ks4], A1, 0, 0, 0);
                B1 = __builtin_amdgcn_mfma_f32_32x32x16_f16(kf1, qfB[ks4], B1, 0, 0, 0);
            }
        }
    };

    auto pv = [&](const char* Vb, f16x8 (&pA)[4], f16x8 (&pB)[4]) {
#pragma unroll
        for (int ksl = 0; ksl < 4; ++ksl) {
            const int off = (ksl * 32 + hi * 16) ^ fsw;
            f16x8 vf0 = *(const f16x8*)(Vb + q31 * 128 + off);
            f16x8 vf1 = *(const f16x8*)(Vb + (32 + q31) * 128 + off);
            OA0 = __builtin_amdgcn_mfma_f32_32x32x16_f16(vf0, pA[ksl], OA0, 0, 0, 0);
            OA1 = __builtin_amdgcn_mfma_f32_32x32x16_f16(vf1, pA[ksl], OA1, 0, 0, 0);
            OB0 = __builtin_amdgcn_mfma_f32_32x32x16_f16(vf0, pB[ksl], OB0, 0, 0, 0);
            OB1 = __builtin_amdgcn_mfma_f32_32x32x16_f16(vf1, pB[ksl], OB1, 0, 0, 0);
        }
    };

    auto soft32 = [&](f32x16& sp, f16x8& paLo, f16x8& paHi, float& ls) {
#pragma unroll
        for (int r = 0; r < 16; ++r) sp[r] = __builtin_amdgcn_exp2f(sp[r]);
        unsigned int u[8];
#pragma unroll
        for (int j = 0; j < 4; ++j) {
            u[2 * j]     = pkrtz(sp[4 * j], sp[4 * j + 1]);
            u[2 * j + 1] = pkrtz(sp[4 * j + 2], sp[4 * j + 3]);
        }
        float ls0 = 0.f, ls1 = 0.f;
#pragma unroll
        for (int j = 0; j < 4; ++j) {
            ls0 = __builtin_amdgcn_fdot2(__builtin_bit_cast(f16x2, u[2 * j]), one2, ls0, false);
            ls1 = __builtin_amdgcn_fdot2(__builtin_bit_cast(f16x2, u[2 * j + 1]), one2, ls1, false);
        }
        ls += ls0 + ls1;
        plswap(u[0], u[2]);
        plswap(u[1], u[3]);
        plswap(u[4], u[6]);
        plswap(u[5], u[7]);
        u32x4 t0w = {u[0], u[1], u[2], u[3]};
        u32x4 t1w = {u[4], u[5], u[6], u[7]};
        paLo = __builtin_bit_cast(f16x8, t0w);
        paHi = __builtin_bit_cast(f16x8, t1w);
    };

    auto body = [&](int t, f16x8 (&pPA)[4], f16x8 (&pPB)[4],
                           f16x8 (&pCA)[4], f16x8 (&pCB)[4]) {
        if (t + 1 < 32) {
            asm volatile("s_waitcnt vmcnt(2)" ::: "memory");
        } else {
            asm volatile("s_waitcnt vmcnt(0)" ::: "memory");
        }
        __builtin_amdgcn_s_barrier();
        if (t + 2 < 32) STAGE((t + 2) & 3, (t + 2) * 64);

        const char* Kb = (const char*)&SM[t & 3][0][0];
        f32x16 sA0, sA1, sB0, sB1;
        if ((w >> 2) == 0) {
            qk(Kb, sA0, sA1, sB0, sB1);
            float lsA = 0.f, lsB = 0.f;
            soft32(sA0, pCA[0], pCA[1], lsA);
            soft32(sB0, pCB[0], pCB[1], lsB);
            soft32(sA1, pCA[2], pCA[3], lsA);
            soft32(sB1, pCB[2], pCB[3], lsB);
            lrA += lsA; lrB += lsB;
            pv((const char*)&SM[t & 3][1][0], pCA, pCB);
        } else {
            if (t > 0) pv((const char*)&SM[(t - 1) & 3][1][0], pPA, pPB);
            qk(Kb, sA0, sA1, sB0, sB1);
            float lsA = 0.f, lsB = 0.f;
            soft32(sA0, pCA[0], pCA[1], lsA);
            soft32(sB0, pCB[0], pCB[1], lsB);
            soft32(sA1, pCA[2], pCA[3], lsA);
            soft32(sB1, pCB[2], pCB[3], lsB);
            lrA += lsA; lrB += lsB;
        }
    };

    STAGE(0, 0);
    STAGE(1, 64);

    f16x8 paEA[4], paEB[4], paOA[4], paOB[4];
#pragma unroll
    for (int i = 0; i < 4; ++i) {
        paOA[i] = (f16x8){};
        paOB[i] = (f16x8){};
    }

    for (int t = 0; t < 32; t += 2) {
        body(t,     paOA, paOB, paEA, paEB);
        body(t + 1, paEA, paEB, paOA, paOB);
    }
    if ((w >> 2) != 0) {
        pv((const char*)&SM[3][1][0], paOA, paOB);
    }
#undef STAGE

    __syncthreads();

    f16* tw = &SM[0][0][0] + w * 4096;
    {
        const float rlA = 1.f / xhalf_sum(lrA);
        const float rlB = 1.f / xhalf_sum(lrB);
#pragma unroll
        for (int f = 0; f < 2; ++f) {
            const float rl = f ? rlB : rlA;
            char* twf = (char*)tw + f * 4096;
#pragma unroll
            for (int dblk = 0; dblk < 2; ++dblk) {
                const f32x16& Op = f ? (dblk ? OB1 : OB0) : (dblk ? OA1 : OA0);
#pragma unroll
                for (int rp = 0; rp < 8; ++rp) {
                    int r = 2 * rp;
                    int d0 = dblk * 32 + (r & 3) + 8 * (r >> 2) + 4 * hi;
                    unsigned int uv = pkrtz(Op[r] * rl, Op[r + 1] * rl);
                    *(unsigned int*)(twf + q31 * 128 + ((d0 * 2) ^ ((q31 & 7) << 4))) = uv;
                }
            }
        }
    }
#pragma unroll
    for (int p4 = 0; p4 < 8; ++p4) {
        int qq = p4 * 8 + (lane >> 3), ch = lane & 7;
        f16x8 v = *(const f16x8*)((const char*)tw + (qq >> 5) * 4096 + (qq & 31) * 128 +
                                  ((ch * 16) ^ ((qq & 7) << 4)));
        *(f16x8*)(ctx + (size_t)(b * SEQ + q0w + qq) * DM + h * DK + ch * 8) = v;
    }
}

extern "C" void kernel_launch(void* const* d_in, const int* in_sizes, int n_in,
                              void* d_out, int out_size, void* d_ws, size_t ws_size,
                              hipStream_t stream) {
    const float* x  = (const float*)d_in[0];
    const float* Wq = (const float*)d_in[1];
    const float* bq = (const float*)d_in[2];
    const float* Wk = (const float*)d_in[3];
    const float* bk = (const float*)d_in[4];
    const float* Wv = (const float*)d_in[5];
    const float* bv = (const float*)d_in[6];
    const float* Wo = (const float*)d_in[7];
    const float* bo = (const float*)d_in[8];

    f16* ws  = (f16*)d_ws;
    f16* xh  = ws;
    f16* Wqh = ws + (size_t)8 * 1024 * 1024;
    f16* Wkh = Wqh + 1024 * 1024;
    f16* Wvh = Wkh + 1024 * 1024;
    f16* Woh = Wvh + 1024 * 1024;
    f16* Vtb = Woh + 1024 * 1024;
    f16* Qb = (f16*)d_out;
    f16* Kb = Qb + (size_t)8 * 1024 * 1024;
    f16* ctx = xh;

    cvt_all<<<4096 + 4 * 512, 256, 0, stream>>>(x, Wq, Wk, Wv, Wo, xh, Wqh, Wkh, Wvh, Woh);

    gemm_qkv8<<<768, 512, 0, stream>>>(xh, Wqh, Wkh, Wvh, bq, bk, bv, Qb, Kb, Vtb);

    attn<<<256, 512, 0, stream>>>(Qb, Kb, Vtb, ctx);

    gemm_out8<<<256, 512, 0, stream>>>(ctx, Woh, bo, (float*)d_out);
}